// Round 6
// baseline (390.540 us; speedup 1.0000x reference)
//
#include <hip/hip_runtime.h>
#include <hip/hip_fp16.h>
#include <math.h>

#define HW    65536
#define TNUM  60
#define NPRED 600
#define NCLS  91
#define PS    128     // pixel slices of 512
#define RTP   20      // row-tile pairs (40 rt of 16 rows, 2 padding)

typedef float f32x4 __attribute__((ext_vector_type(4)));
typedef short s16x8 __attribute__((ext_vector_type(8)));

// ================= K0a: target stats partials (cnt + masks_to_boxes) ==========
__global__ void hm_tgt_stats(const int* __restrict__ tm, float* __restrict__ tstat) {
    int j = blockIdx.x >> 3, chunk = blockIdx.x & 7;
    int tid = threadIdx.x;
    const int* row = tm + (size_t)j * HW + chunk * 8192;
    float cnt = 0.f, xmax = -INFINITY, ymax = -INFINITY, xmin = INFINITY, ymin = INFINITY;
    for (int i = tid; i < 8192; i += 256) {
        int pix = chunk * 8192 + i;
        float t = (float)row[i];
        float xf = (float)(pix & 255), yf = (float)(pix >> 8);
        float xm = t * xf, ym = t * yf;
        cnt += t;
        xmax = fmaxf(xmax, xm); ymax = fmaxf(ymax, ym);
        bool nz = (t != 0.f);
        xmin = fminf(xmin, nz ? xm : 1e8f);
        ymin = fminf(ymin, nz ? ym : 1e8f);
    }
#pragma unroll
    for (int o = 1; o < 64; o <<= 1) {
        cnt += __shfl_xor(cnt, o);
        xmax = fmaxf(xmax, __shfl_xor(xmax, o));
        ymax = fmaxf(ymax, __shfl_xor(ymax, o));
        xmin = fminf(xmin, __shfl_xor(xmin, o));
        ymin = fminf(ymin, __shfl_xor(ymin, o));
    }
    __shared__ float s[5][4];
    int w = tid >> 6;
    if ((tid & 63) == 0) { s[0][w]=cnt; s[1][w]=xmin; s[2][w]=ymin; s[3][w]=xmax; s[4][w]=ymax; }
    __syncthreads();
    if (tid == 0) {
        float* o = tstat + (size_t)(j * 8 + chunk) * 5;
        o[0] = s[0][0]+s[0][1]+s[0][2]+s[0][3];
        o[1] = fminf(fminf(s[1][0],s[1][1]),fminf(s[1][2],s[1][3]));
        o[2] = fminf(fminf(s[2][0],s[2][1]),fminf(s[2][2],s[2][3]));
        o[3] = fmaxf(fmaxf(s[3][0],s[3][1]),fmaxf(s[3][2],s[3][3]));
        o[4] = fmaxf(fmaxf(s[4][0],s[4][1]),fmaxf(s[4][2],s[4][3]));
    }
}

// ================= K0b: build Tpack in B-fragment order ======================
// Tpack ushort index: (kb*64 + j)*32 + g*8 + e   where pixel = kb*32 + g*8 + e
__global__ void hm_build_tpack(const int* __restrict__ tm, unsigned short* __restrict__ tp) {
    int bid = blockIdx.x;                 // 64 * 256 blocks
    int j = bid >> 8, chunk = bid & 255;
    int pix = chunk * 256 + threadIdx.x;
    unsigned short v = 0;
    if (j < TNUM) v = (tm[(size_t)j * HW + pix] != 0) ? (unsigned short)0x3F80 : (unsigned short)0;
    size_t idx = ((size_t)(pix >> 5) * 64 + j) * 32 + (size_t)((pix >> 3) & 3) * 8 + (pix & 7);
    tp[idx] = v;
}

// ================= K1: heavy fused MFMA kernel ===============================
__device__ inline void pix_proc(float x, int e, float xfb, float yf,
                                __bf16* P, __bf16* F,
                                float& sp, float& sn,
                                float& xM, float& yM, float& xm, float& ym) {
    float ex = __expf(x);
    float opex = 1.f + ex;
    float om = __builtin_amdgcn_rcpf(opex);   // 1 - p
    float p = 1.f - om;
    float spx = __logf(opex);      // -log(1-p)
    float spmx = spx - x;          // -log(p)
    float pos = (om * om) * (0.25f * spmx);
    float neg = (p * p) * (0.75f * spx);
    sp += p; sn += neg;
    float xf = xfb + (float)e;
    float xmsk = x * xf, ymsk = x * yf;
    xM = fmaxf(xM, xmsk); yM = fmaxf(yM, ymsk);
    bool nz = (x != 0.f);
    xm = fminf(xm, nz ? xmsk : 1e8f);
    ym = fminf(ym, nz ? ymsk : 1e8f);
    P[e] = (__bf16)p;
    F[e] = (__bf16)(pos - neg);
}

// grid: 2560 blocks of 128 (2 independent waves). XCD-swizzled:
// xcd=id&7, q=id>>3, rtp=q%20, psg=q/20, ps=xcd+8*psg. All 20 blocks
// sharing a ps-slice of tpack land on one XCD (1MB/XCD, L2-resident).
// Wave w owns rows rt=rtp*2+w (16 rows) over pixels [ps*512, ps*512+512).
// No LDS, no barriers. Dots stored FRAGMENT-LINEAR (lane-contiguous 256B
// per store instruction) -- decode happens in hm_combine.
__launch_bounds__(128, 8)
__global__ void hm_heavy(const float* __restrict__ pm, const unsigned short* __restrict__ tp,
                         __half2* __restrict__ dots, float* __restrict__ stats) {
    int id = blockIdx.x;
    int xcd = id & 7, q = id >> 3;
    int rtp = q % RTP, psg = q / RTP;
    int ps = xcd + 8 * psg;               // [0,128)
    int tid = threadIdx.x, w = tid >> 6, l = tid & 63, g = l >> 4, c = l & 15;
    int rt = rtp * 2 + w;                 // [0,40)
    int row = min(rt * 16 + c, NPRED - 1);
    const float* A = pm + (size_t)row * HW;
    const s16x8* tpv = (const s16x8*)tp;
    int pb = ps * 512;

    f32x4 acc[4][2];
#pragma unroll
    for (int nt = 0; nt < 4; ++nt)
#pragma unroll
        for (int m = 0; m < 2; ++m) acc[nt][m] = (f32x4)0.f;

    float sp = 0.f, sn = 0.f;
    float xM = -INFINITY, yM = -INFINITY, xm = INFINITY, ym = INFINITY;

#pragma unroll 2
    for (int step = 0; step < 16; ++step) {
        int k0 = pb + step * 32;
        int kk = k0 + g * 8;
        float4 aa = *(const float4*)(A + kk);
        float4 ab = *(const float4*)(A + kk + 4);
        float yf = (float)(kk >> 8);
        float xfb = (float)(kk & 255);

        union { __bf16 h[8]; s16x8 v; } P, F;
        float x[8] = {aa.x, aa.y, aa.z, aa.w, ab.x, ab.y, ab.z, ab.w};
#pragma unroll
        for (int e = 0; e < 8; ++e)
            pix_proc(x[e], e, xfb, yf, P.h, F.h, sp, sn, xM, yM, xm, ym);

        int bbase = (k0 >> 5) * 256 + c * 4 + g;
#pragma unroll
        for (int nt = 0; nt < 4; ++nt) {
            s16x8 bf = tpv[bbase + nt * 64];
            acc[nt][0] = __builtin_amdgcn_mfma_f32_16x16x32_bf16(P.v, bf, acc[nt][0], 0, 0, 0);
            acc[nt][1] = __builtin_amdgcn_mfma_f32_16x16x32_bf16(F.v, bf, acc[nt][1], 0, 0, 0);
        }
    }

    // per-row stats: reduce over the 4 g-groups (lanes c, c+16, c+32, c+48)
#pragma unroll
    for (int o = 16; o <= 32; o <<= 1) {
        sp += __shfl_xor(sp, o); sn += __shfl_xor(sn, o);
        xM = fmaxf(xM, __shfl_xor(xM, o)); yM = fmaxf(yM, __shfl_xor(yM, o));
        xm = fminf(xm, __shfl_xor(xm, o)); ym = fminf(ym, __shfl_xor(ym, o));
    }
    if (l < 16) {
        float* so = stats + ((size_t)(rt * PS + ps) * 16 + l) * 6;
        so[0] = sp; so[1] = sn; so[2] = xM; so[3] = yM; so[4] = xm; so[5] = ym;
    }

    // dots fragment-linear: [rt][ps][(nt*4+r)*64 + lane] of half2{dotP, dotF}.
    // Each store: 64 lanes x 4B contiguous = 256B coalesced.
    size_t dbase = (size_t)(rt * PS + ps) * 1024;
#pragma unroll
    for (int nt = 0; nt < 4; ++nt)
#pragma unroll
        for (int r = 0; r < 4; ++r) {
            __half2 h;
            h.x = __float2half_rn(acc[nt][0][r]);
            h.y = __float2half_rn(acc[nt][1][r]);
            dots[dbase + (size_t)((nt * 4 + r) * 64 + l)] = h;
        }
}

// ================= K2: reduce pred stats over PS slices ======================
__global__ void hm_pred_reduce(const float* __restrict__ stats, float* __restrict__ pstat) {
    int n = blockIdx.x;            // 600
    int l = threadIdx.x;           // 64
    int rt = n >> 4, r = n & 15;
    const float* s0 = stats + ((size_t)(rt * PS + l) * 16 + r) * 6;
    const float* s1 = stats + ((size_t)(rt * PS + l + 64) * 16 + r) * 6;
    float v0 = s0[0] + s1[0];
    float v1 = s0[1] + s1[1];
    float v2 = fmaxf(s0[2], s1[2]);
    float v3 = fmaxf(s0[3], s1[3]);
    float v4 = fminf(s0[4], s1[4]);
    float v5 = fminf(s0[5], s1[5]);
#pragma unroll
    for (int o = 1; o < 64; o <<= 1) {
        v0 += __shfl_xor(v0, o); v1 += __shfl_xor(v1, o);
        v2 = fmaxf(v2, __shfl_xor(v2, o)); v3 = fmaxf(v3, __shfl_xor(v3, o));
        v4 = fminf(v4, __shfl_xor(v4, o)); v5 = fminf(v5, __shfl_xor(v5, o));
    }
    if (l == 0) {
        float* o = pstat + (size_t)n * 6;
        o[0] = v0; o[1] = v1; o[2] = v2; o[3] = v3; o[4] = v4; o[5] = v5;
    }
}

// ================= helpers ===================================================
__device__ inline float giou2(float ax0, float ay0, float ax1, float ay1,
                              float bx0, float by0, float bx1, float by1) {
    float area1 = (ax1 - ax0) * (ay1 - ay0);
    float area2 = (bx1 - bx0) * (by1 - by0);
    float ltx = fmaxf(ax0, bx0), lty = fmaxf(ay0, by0);
    float rbx = fminf(ax1, bx1), rby = fminf(ay1, by1);
    float iw = fmaxf(rbx - ltx, 0.f), ih = fmaxf(rby - lty, 0.f);
    float inter = iw * ih;
    float uni = area1 + area2 - inter;
    float iou = inter / uni;
    float ex0 = fminf(ax0, bx0), ey0 = fminf(ay0, by0);
    float ex1 = fmaxf(ax1, bx1), ey1 = fmaxf(ay1, by1);
    float ew = fmaxf(ex1 - ex0, 0.f), eh = fmaxf(ey1 - ey0, 0.f);
    float ae = ew * eh;
    return iou - (ae - uni) / ae;
}

__device__ inline float giou_cxcywh(float acx, float acy, float aw, float ah,
                                    float bcx, float bcy, float bw, float bh) {
    return giou2(acx - 0.5f * aw, acy - 0.5f * ah, acx + 0.5f * aw, acy + 0.5f * ah,
                 bcx - 0.5f * bw, bcy - 0.5f * bh, bcx + 0.5f * bw, bcy + 0.5f * bh);
}

// ================= K3: final combine =========================================
__global__ void hm_combine(const float* __restrict__ pred_logits,
                           const float* __restrict__ pred_boxes,
                           const float* __restrict__ tgt_boxes,
                           const int* __restrict__ tgt_ids,
                           const __half2* __restrict__ dots,
                           const float* __restrict__ pstat,
                           const float* __restrict__ tstat,
                           float* __restrict__ out) {
    int idx = blockIdx.x * blockDim.x + threadIdx.x;
    if (idx >= NPRED * TNUM) return;
    int n = idx / TNUM, j = idx % TNUM;
    int rt = n >> 4, rr = n & 15;
    int g = rr >> 2, r = rr & 3, nt = j >> 4, c = j & 15;
    int elem = (nt * 4 + r) * 64 + g * 16 + c;   // fragment-linear decode

    // reduce dot partials over PS pixel slices
    const __half2* db = dots + (size_t)(rt * PS) * 1024 + elem;
    float dp = 0.f, df = 0.f;
#pragma unroll 8
    for (int ps = 0; ps < PS; ++ps) {
        __half2 v = db[(size_t)ps * 1024];
        dp += __half2float(v.x);
        df += __half2float(v.y);
    }

    // reduce target stats over 8 chunks
    float tcnt = 0.f, txm = INFINITY, tym = INFINITY, txM = -INFINITY, tyM = -INFINITY;
#pragma unroll
    for (int k = 0; k < 8; ++k) {
        const float* tb = tstat + (size_t)(j * 8 + k) * 5;
        tcnt += tb[0];
        txm = fminf(txm, tb[1]); tym = fminf(tym, tb[2]);
        txM = fmaxf(txM, tb[3]); tyM = fmaxf(tyM, tb[4]);
    }

    const float* pp = pstat + (size_t)n * 6;
    float sum_p = pp[0], sum_neg = pp[1];
    float pxM = pp[2], pyM = pp[3], pxm = pp[4], pym = pp[5];

    // L1 bbox cost
    float4 ob = ((const float4*)pred_boxes)[n];
    float4 tb4 = ((const float4*)tgt_boxes)[j];
    float cbbox = fabsf(ob.x - tb4.x) + fabsf(ob.y - tb4.y) + fabsf(ob.z - tb4.z) + fabsf(ob.w - tb4.w);

    // GIoU cost (cxcywh boxes)
    float cgiou = -giou_cxcywh(ob.x, ob.y, ob.z, ob.w, tb4.x, tb4.y, tb4.z, tb4.w);

    // focal classification cost
    int id = tgt_ids[j];
    float lg = pred_logits[(size_t)n * NCLS + id];
    float e = __expf(lg);
    float pr = __fdividef(e, 1.f + e);
    float poscc = 0.25f * (1.f - pr) * (1.f - pr) * (-__logf(pr + 1e-8f));
    float negcc = 0.75f * pr * pr * (-__logf(1.f - pr + 1e-8f));
    float cclass = poscc - negcc;

    // GIoU on mask-derived boxes (faithfully fed through cxcywh conversion)
    float cm2b = -giou_cxcywh(pxm, pym, pxM, pyM, txm, tym, txM, tyM);

    // dice
    float un = sum_p + tcnt;
    float cdice = 1.f - (2.f * dp + 1e-5f) / (un + 1e-5f);

    // mask focal
    float cfocal = (df + sum_neg) * (1.0f / (float)HW);

    out[idx] = cbbox + cclass + cgiou + cm2b + cdice + cfocal;
}

// ================= launcher ==================================================
extern "C" void kernel_launch(void* const* d_in, const int* in_sizes, int n_in,
                              void* d_out, int out_size, void* d_ws, size_t ws_size,
                              hipStream_t stream) {
    const float* pred_logits = (const float*)d_in[0];
    const float* pred_boxes  = (const float*)d_in[1];
    const float* pred_masks  = (const float*)d_in[2];
    const float* tgt_boxes   = (const float*)d_in[3];
    const int*   tgt_ids     = (const int*)d_in[4];
    const int*   tgt_masks   = (const int*)d_in[5];
    float* out = (float*)d_out;

    char* wsb = (char*)d_ws;
    unsigned short* tpack = (unsigned short*)wsb;          // 64*HW*2            =  8,388,608 B
    __half2* dots = (__half2*)(wsb + 8388608);             // 40*128*16*64*4     = 20,971,520 B
    float* stats  = (float*)(wsb + 29360128);              // 40*128*16*6*4      =  1,966,080 B
    float* pstat  = (float*)(wsb + 31326208);              // 600*6*4            =     14,400 B
    float* tstat  = (float*)(wsb + 31340608);              // 480*5*4            =      9,600 B
                                                           // total ~31.35 MB

    hipLaunchKernelGGL(hm_tgt_stats, dim3(TNUM * 8), dim3(256), 0, stream, tgt_masks, tstat);
    hipLaunchKernelGGL(hm_build_tpack, dim3(64 * 256), dim3(256), 0, stream, tgt_masks, tpack);
    hipLaunchKernelGGL(hm_heavy, dim3(RTP * PS), dim3(128), 0, stream, pred_masks, tpack, dots, stats);
    hipLaunchKernelGGL(hm_pred_reduce, dim3(NPRED), dim3(64), 0, stream, stats, pstat);
    hipLaunchKernelGGL(hm_combine, dim3((NPRED * TNUM + 255) / 256), dim3(256), 0, stream,
                       pred_logits, pred_boxes, tgt_boxes, tgt_ids, dots, pstat, tstat, out);
}

// Round 7
// 221.348 us; speedup vs baseline: 1.7644x; 1.7644x over previous
//
#include <hip/hip_runtime.h>
#include <math.h>

#define HW    65536
#define TNUM  60
#define NPRED 600
#define NCLS  91
#define PS    64      // pixel slices of 1024
#define NTIL  38      // ceil(600/16) M-tiles of 16

typedef float f32x4 __attribute__((ext_vector_type(4)));
typedef short s16x8 __attribute__((ext_vector_type(8)));

// ================= K0a: target stats partials (cnt + masks_to_boxes) ==========
__global__ void hm_tgt_stats(const int* __restrict__ tm, float* __restrict__ tstat) {
    int j = blockIdx.x >> 3, chunk = blockIdx.x & 7;
    int tid = threadIdx.x;
    const int* row = tm + (size_t)j * HW + chunk * 8192;
    float cnt = 0.f, xmax = -INFINITY, ymax = -INFINITY, xmin = INFINITY, ymin = INFINITY;
    for (int i = tid; i < 8192; i += 256) {
        int pix = chunk * 8192 + i;
        float t = (float)row[i];
        float xf = (float)(pix & 255), yf = (float)(pix >> 8);
        float xm = t * xf, ym = t * yf;
        cnt += t;
        xmax = fmaxf(xmax, xm); ymax = fmaxf(ymax, ym);
        bool nz = (t != 0.f);
        xmin = fminf(xmin, nz ? xm : 1e8f);
        ymin = fminf(ymin, nz ? ym : 1e8f);
    }
#pragma unroll
    for (int o = 1; o < 64; o <<= 1) {
        cnt += __shfl_xor(cnt, o);
        xmax = fmaxf(xmax, __shfl_xor(xmax, o));
        ymax = fmaxf(ymax, __shfl_xor(ymax, o));
        xmin = fminf(xmin, __shfl_xor(xmin, o));
        ymin = fminf(ymin, __shfl_xor(ymin, o));
    }
    __shared__ float s[5][4];
    int w = tid >> 6;
    if ((tid & 63) == 0) { s[0][w]=cnt; s[1][w]=xmin; s[2][w]=ymin; s[3][w]=xmax; s[4][w]=ymax; }
    __syncthreads();
    if (tid == 0) {
        float* o = tstat + (size_t)(j * 8 + chunk) * 5;
        o[0] = s[0][0]+s[0][1]+s[0][2]+s[0][3];
        o[1] = fminf(fminf(s[1][0],s[1][1]),fminf(s[1][2],s[1][3]));
        o[2] = fminf(fminf(s[2][0],s[2][1]),fminf(s[2][2],s[2][3]));
        o[3] = fmaxf(fmaxf(s[3][0],s[3][1]),fmaxf(s[3][2],s[3][3]));
        o[4] = fmaxf(fmaxf(s[4][0],s[4][1]),fmaxf(s[4][2],s[4][3]));
    }
}

// ================= K0b: build Tpack in B-fragment order ======================
// Tpack ushort index: (kb*64 + j)*32 + g*8 + e   where pixel = kb*32 + g*8 + e
__global__ void hm_build_tpack(const int* __restrict__ tm, unsigned short* __restrict__ tp) {
    int bid = blockIdx.x;                 // 64 * 256 blocks
    int j = bid >> 8, chunk = bid & 255;
    int pix = chunk * 256 + threadIdx.x;
    unsigned short v = 0;
    if (j < TNUM) v = (tm[(size_t)j * HW + pix] != 0) ? (unsigned short)0x3F80 : (unsigned short)0;
    size_t idx = ((size_t)(pix >> 5) * 64 + j) * 32 + (size_t)((pix >> 3) & 3) * 8 + (pix & 7);
    tp[idx] = v;
}

// ================= K1: heavy fused MFMA kernel ===============================
__device__ inline void pix_proc(float x, int e, float xfb, float yf,
                                __bf16* P, __bf16* F,
                                float& sp, float& sn,
                                float& xM, float& yM, float& xm, float& ym) {
    float ex = __expf(x);
    float opex = 1.f + ex;
    float om = __builtin_amdgcn_rcpf(opex);   // 1 - p
    float p = 1.f - om;
    float spx = __logf(opex);      // -log(1-p)
    float spmx = spx - x;          // -log(p)
    float pos = (om * om) * (0.25f * spmx);
    float neg = (p * p) * (0.75f * spx);
    sp += p; sn += neg;
    float xf = xfb + (float)e;
    float xmsk = x * xf, ymsk = x * yf;
    xM = fmaxf(xM, xmsk); yM = fmaxf(yM, ymsk);
    bool nz = (x != 0.f);
    xm = fminf(xm, nz ? xmsk : 1e8f);
    ym = fminf(ym, nz ? ymsk : 1e8f);
    P[e] = (__bf16)p;
    F[e] = (__bf16)(pos - neg);
}

// grid: NTIL*PS = 2432 blocks of 256. XCD-swizzled: xcd=id&7, q=id>>3,
// ntile=q%38, psg=q/38 (0..7), ps=xcd+8*psg. All 38 blocks sharing a
// ps-slice of tpack land on one XCD (2MB/XCD slice group, L2-resident).
// Wave w owns pixels [ps*1024 + w*256, +256). A rows = ntile*16..+15.
// 16KB LDS (two-phase epilogue) -> up to 8 blocks/CU co-resident.
__launch_bounds__(256, 6)
__global__ void hm_heavy(const float* __restrict__ pm, const unsigned short* __restrict__ tp,
                         float* __restrict__ dots, float* __restrict__ stats) {
    int id = blockIdx.x;
    int xcd = id & 7, q = id >> 3;
    int ntile = q % NTIL, psg = q / NTIL;
    int ps = xcd + 8 * psg;               // [0,64)
    int bl = ntile * PS + ps;             // logical block index
    int tid = threadIdx.x, w = tid >> 6, l = tid & 63, g = l >> 4, c = l & 15;
    int n0 = ntile * 16;
    int row = min(n0 + c, NPRED - 1);
    const float* A = pm + (size_t)row * HW;
    const s16x8* tpv = (const s16x8*)tp;
    int pb = ps * 1024 + w * 256;

    f32x4 acc[4][2];
#pragma unroll
    for (int nt = 0; nt < 4; ++nt)
#pragma unroll
        for (int m = 0; m < 2; ++m) acc[nt][m] = (f32x4)0.f;

    float sp = 0.f, sn = 0.f;
    float xM = -INFINITY, yM = -INFINITY, xm = INFINITY, ym = INFINITY;

#pragma unroll 2
    for (int step = 0; step < 8; ++step) {
        int k0 = pb + step * 32;
        int kk = k0 + g * 8;
        float4 aa = *(const float4*)(A + kk);
        float4 ab = *(const float4*)(A + kk + 4);
        float yf = (float)(kk >> 8);
        float xfb = (float)(kk & 255);

        union { __bf16 h[8]; s16x8 v; } P, F;
        float x[8] = {aa.x, aa.y, aa.z, aa.w, ab.x, ab.y, ab.z, ab.w};
#pragma unroll
        for (int e = 0; e < 8; ++e)
            pix_proc(x[e], e, xfb, yf, P.h, F.h, sp, sn, xM, yM, xm, ym);

        int bbase = (k0 >> 5) * 256 + c * 4 + g;
#pragma unroll
        for (int nt = 0; nt < 4; ++nt) {
            s16x8 bf = tpv[bbase + nt * 64];
            acc[nt][0] = __builtin_amdgcn_mfma_f32_16x16x32_bf16(P.v, bf, acc[nt][0], 0, 0, 0);
            acc[nt][1] = __builtin_amdgcn_mfma_f32_16x16x32_bf16(F.v, bf, acc[nt][1], 0, 0, 0);
        }
    }

    // reduce per-row stats over the 4 g-groups (lanes c, c+16, c+32, c+48: same row)
#pragma unroll
    for (int o = 16; o <= 32; o <<= 1) {
        sp += __shfl_xor(sp, o); sn += __shfl_xor(sn, o);
        xM = fmaxf(xM, __shfl_xor(xM, o)); yM = fmaxf(yM, __shfl_xor(yM, o));
        xm = fminf(xm, __shfl_xor(xm, o)); ym = fminf(ym, __shfl_xor(ym, o));
    }

    __shared__ float ldsD[4][16][64];   // 16 KiB, reused across phases
    // ---- phase A: mat=0 (P dots) ----
#pragma unroll
    for (int nt = 0; nt < 4; ++nt)
#pragma unroll
        for (int r = 0; r < 4; ++r)
            ldsD[w][nt * 4 + r][l] = acc[nt][0][r];
    __syncthreads();
    for (int idx = tid; idx < 1024; idx += 256) {
        int rl = (idx >> 6) & 15, col = idx & 63;
        int gg = rl >> 2, rg = rl & 3;
        int nt = col >> 4, cc = col & 15;
        int lane = gg * 16 + cc;
        int off = nt * 4 + rg;
        float s = ldsD[0][off][lane] + ldsD[1][off][lane] + ldsD[2][off][lane] + ldsD[3][off][lane];
        dots[(size_t)bl * 2048 + idx] = s;
    }
    __syncthreads();
    // ---- phase B: mat=1 (F dots) ----
#pragma unroll
    for (int nt = 0; nt < 4; ++nt)
#pragma unroll
        for (int r = 0; r < 4; ++r)
            ldsD[w][nt * 4 + r][l] = acc[nt][1][r];
    __syncthreads();
    for (int idx = tid; idx < 1024; idx += 256) {
        int rl = (idx >> 6) & 15, col = idx & 63;
        int gg = rl >> 2, rg = rl & 3;
        int nt = col >> 4, cc = col & 15;
        int lane = gg * 16 + cc;
        int off = nt * 4 + rg;
        float s = ldsD[0][off][lane] + ldsD[1][off][lane] + ldsD[2][off][lane] + ldsD[3][off][lane];
        dots[(size_t)bl * 2048 + 1024 + idx] = s;
    }
    __syncthreads();
    // ---- stats phase (alias the same LDS) ----
    float* ldsS = (float*)ldsD;          // [w][row16][6] flat = w*96 + l*6 + s
    if (l < 16) {
        float* so = ldsS + w * 96 + l * 6;
        so[0] = sp; so[1] = sn; so[2] = xM; so[3] = yM; so[4] = xm; so[5] = ym;
    }
    __syncthreads();
    if (tid < 96) {
        int rr = tid / 6, s = tid % 6;
        float a0 = ldsS[0 * 96 + rr * 6 + s], a1 = ldsS[1 * 96 + rr * 6 + s];
        float a2 = ldsS[2 * 96 + rr * 6 + s], a3 = ldsS[3 * 96 + rr * 6 + s];
        float r;
        if (s < 2)      r = a0 + a1 + a2 + a3;
        else if (s < 4) r = fmaxf(fmaxf(a0, a1), fmaxf(a2, a3));
        else            r = fminf(fminf(a0, a1), fminf(a2, a3));
        stats[(size_t)(bl * 16 + rr) * 6 + s] = r;
    }
}

// ================= K2: reduce pred stats over PS slices ======================
__global__ void hm_pred_reduce(const float* __restrict__ stats, float* __restrict__ pstat) {
    int n = blockIdx.x;            // 600
    int l = threadIdx.x;           // 64 (one per ps slice)
    int ntile = n >> 4, r = n & 15;
    const float* sb = stats + ((size_t)((ntile * PS + l) * 16 + r)) * 6;
    float v0 = sb[0], v1 = sb[1], v2 = sb[2], v3 = sb[3], v4 = sb[4], v5 = sb[5];
#pragma unroll
    for (int o = 1; o < 64; o <<= 1) {
        v0 += __shfl_xor(v0, o); v1 += __shfl_xor(v1, o);
        v2 = fmaxf(v2, __shfl_xor(v2, o)); v3 = fmaxf(v3, __shfl_xor(v3, o));
        v4 = fminf(v4, __shfl_xor(v4, o)); v5 = fminf(v5, __shfl_xor(v5, o));
    }
    if (l == 0) {
        float* o = pstat + (size_t)n * 6;
        o[0] = v0; o[1] = v1; o[2] = v2; o[3] = v3; o[4] = v4; o[5] = v5;
    }
}

// ================= helpers ===================================================
__device__ inline float giou2(float ax0, float ay0, float ax1, float ay1,
                              float bx0, float by0, float bx1, float by1) {
    float area1 = (ax1 - ax0) * (ay1 - ay0);
    float area2 = (bx1 - bx0) * (by1 - by0);
    float ltx = fmaxf(ax0, bx0), lty = fmaxf(ay0, by0);
    float rbx = fminf(ax1, bx1), rby = fminf(ay1, by1);
    float iw = fmaxf(rbx - ltx, 0.f), ih = fmaxf(rby - lty, 0.f);
    float inter = iw * ih;
    float uni = area1 + area2 - inter;
    float iou = inter / uni;
    float ex0 = fminf(ax0, bx0), ey0 = fminf(ay0, by0);
    float ex1 = fmaxf(ax1, bx1), ey1 = fmaxf(ay1, by1);
    float ew = fmaxf(ex1 - ex0, 0.f), eh = fmaxf(ey1 - ey0, 0.f);
    float ae = ew * eh;
    return iou - (ae - uni) / ae;
}

__device__ inline float giou_cxcywh(float acx, float acy, float aw, float ah,
                                    float bcx, float bcy, float bw, float bh) {
    return giou2(acx - 0.5f * aw, acy - 0.5f * ah, acx + 0.5f * aw, acy + 0.5f * ah,
                 bcx - 0.5f * bw, bcy - 0.5f * bh, bcx + 0.5f * bw, bcy + 0.5f * bh);
}

// ================= K3: final combine =========================================
__global__ void hm_combine(const float* __restrict__ pred_logits,
                           const float* __restrict__ pred_boxes,
                           const float* __restrict__ tgt_boxes,
                           const int* __restrict__ tgt_ids,
                           const float* __restrict__ dots,
                           const float* __restrict__ pstat,
                           const float* __restrict__ tstat,
                           float* __restrict__ out) {
    int idx = blockIdx.x * blockDim.x + threadIdx.x;
    if (idx >= NPRED * TNUM) return;
    int n = idx / TNUM, j = idx % TNUM;
    int ntile = n >> 4, r = n & 15;

    // reduce dot partials over PS pixel slices; per-block layout [mat][row16][col64]
    const float* db = dots + (size_t)ntile * PS * 2048 + r * 64 + j;
    float dp = 0.f, df = 0.f;
#pragma unroll
    for (int ps = 0; ps < PS; ++ps) {
        dp += db[ps * 2048];
        df += db[ps * 2048 + 1024];
    }

    // reduce target stats over 8 chunks
    float tcnt = 0.f, txm = INFINITY, tym = INFINITY, txM = -INFINITY, tyM = -INFINITY;
#pragma unroll
    for (int k = 0; k < 8; ++k) {
        const float* tb = tstat + (size_t)(j * 8 + k) * 5;
        tcnt += tb[0];
        txm = fminf(txm, tb[1]); tym = fminf(tym, tb[2]);
        txM = fmaxf(txM, tb[3]); tyM = fmaxf(tyM, tb[4]);
    }

    const float* pp = pstat + (size_t)n * 6;
    float sum_p = pp[0], sum_neg = pp[1];
    float pxM = pp[2], pyM = pp[3], pxm = pp[4], pym = pp[5];

    // L1 bbox cost
    float4 ob = ((const float4*)pred_boxes)[n];
    float4 tb4 = ((const float4*)tgt_boxes)[j];
    float cbbox = fabsf(ob.x - tb4.x) + fabsf(ob.y - tb4.y) + fabsf(ob.z - tb4.z) + fabsf(ob.w - tb4.w);

    // GIoU cost (cxcywh boxes)
    float cgiou = -giou_cxcywh(ob.x, ob.y, ob.z, ob.w, tb4.x, tb4.y, tb4.z, tb4.w);

    // focal classification cost
    int id = tgt_ids[j];
    float lg = pred_logits[(size_t)n * NCLS + id];
    float e = __expf(lg);
    float pr = __fdividef(e, 1.f + e);
    float poscc = 0.25f * (1.f - pr) * (1.f - pr) * (-__logf(pr + 1e-8f));
    float negcc = 0.75f * pr * pr * (-__logf(1.f - pr + 1e-8f));
    float cclass = poscc - negcc;

    // GIoU on mask-derived boxes (faithfully fed through cxcywh conversion)
    float cm2b = -giou_cxcywh(pxm, pym, pxM, pyM, txm, tym, txM, tyM);

    // dice
    float un = sum_p + tcnt;
    float cdice = 1.f - (2.f * dp + 1e-5f) / (un + 1e-5f);

    // mask focal
    float cfocal = (df + sum_neg) * (1.0f / (float)HW);

    out[idx] = cbbox + cclass + cgiou + cm2b + cdice + cfocal;
}

// ================= launcher ==================================================
extern "C" void kernel_launch(void* const* d_in, const int* in_sizes, int n_in,
                              void* d_out, int out_size, void* d_ws, size_t ws_size,
                              hipStream_t stream) {
    const float* pred_logits = (const float*)d_in[0];
    const float* pred_boxes  = (const float*)d_in[1];
    const float* pred_masks  = (const float*)d_in[2];
    const float* tgt_boxes   = (const float*)d_in[3];
    const int*   tgt_ids     = (const int*)d_in[4];
    const int*   tgt_masks   = (const int*)d_in[5];
    float* out = (float*)d_out;

    char* wsb = (char*)d_ws;
    unsigned short* tpack = (unsigned short*)wsb;          // 64*HW*2           =  8,388,608 B
    float* dots  = (float*)(wsb + 8388608);                // 2432*2048*4       = 19,922,944 B
    float* stats = (float*)(wsb + 28311552);               // 2432*16*6*4       =    933,888 B
    float* pstat = (float*)(wsb + 29245440);               // 600*6*4           =     14,400 B
    float* tstat = (float*)(wsb + 29259840);               // 480*5*4           =      9,600 B
                                                           // total ~29.27 MB

    hipLaunchKernelGGL(hm_tgt_stats, dim3(TNUM * 8), dim3(256), 0, stream, tgt_masks, tstat);
    hipLaunchKernelGGL(hm_build_tpack, dim3(64 * 256), dim3(256), 0, stream, tgt_masks, tpack);
    hipLaunchKernelGGL(hm_heavy, dim3(NTIL * PS), dim3(256), 0, stream, pred_masks, tpack, dots, stats);
    hipLaunchKernelGGL(hm_pred_reduce, dim3(NPRED), dim3(64), 0, stream, stats, pstat);
    hipLaunchKernelGGL(hm_combine, dim3((NPRED * TNUM + 255) / 256), dim3(256), 0, stream,
                       pred_logits, pred_boxes, tgt_boxes, tgt_ids, dots, pstat, tstat, out);
}

// Round 8
// 180.378 us; speedup vs baseline: 2.1651x; 1.2271x over previous
//
#include <hip/hip_runtime.h>
#include <math.h>

#define HW    65536
#define TNUM  60
#define NPRED 600
#define NCLS  91
#define PS    64      // pixel slices of 1024
#define NTIL  38      // ceil(600/16) M-tiles of 16
#define NROWP 608     // padded rows (38*16)

typedef float f32x4 __attribute__((ext_vector_type(4)));
typedef short s16x8 __attribute__((ext_vector_type(8)));

// ================= K0a: target stats partials (cnt + masks_to_boxes) ==========
__global__ void hm_tgt_stats(const int* __restrict__ tm, float* __restrict__ tstat) {
    int j = blockIdx.x >> 3, chunk = blockIdx.x & 7;
    int tid = threadIdx.x;
    const int* row = tm + (size_t)j * HW + chunk * 8192;
    float cnt = 0.f, xmax = -INFINITY, ymax = -INFINITY, xmin = INFINITY, ymin = INFINITY;
    for (int i = tid; i < 8192; i += 256) {
        int pix = chunk * 8192 + i;
        float t = (float)row[i];
        float xf = (float)(pix & 255), yf = (float)(pix >> 8);
        float xm = t * xf, ym = t * yf;
        cnt += t;
        xmax = fmaxf(xmax, xm); ymax = fmaxf(ymax, ym);
        bool nz = (t != 0.f);
        xmin = fminf(xmin, nz ? xm : 1e8f);
        ymin = fminf(ymin, nz ? ym : 1e8f);
    }
#pragma unroll
    for (int o = 1; o < 64; o <<= 1) {
        cnt += __shfl_xor(cnt, o);
        xmax = fmaxf(xmax, __shfl_xor(xmax, o));
        ymax = fmaxf(ymax, __shfl_xor(ymax, o));
        xmin = fminf(xmin, __shfl_xor(xmin, o));
        ymin = fminf(ymin, __shfl_xor(ymin, o));
    }
    __shared__ float s[5][4];
    int w = tid >> 6;
    if ((tid & 63) == 0) { s[0][w]=cnt; s[1][w]=xmin; s[2][w]=ymin; s[3][w]=xmax; s[4][w]=ymax; }
    __syncthreads();
    if (tid == 0) {
        float* o = tstat + (size_t)(j * 8 + chunk) * 5;
        o[0] = s[0][0]+s[0][1]+s[0][2]+s[0][3];
        o[1] = fminf(fminf(s[1][0],s[1][1]),fminf(s[1][2],s[1][3]));
        o[2] = fminf(fminf(s[2][0],s[2][1]),fminf(s[2][2],s[2][3]));
        o[3] = fmaxf(fmaxf(s[3][0],s[3][1]),fmaxf(s[3][2],s[3][3]));
        o[4] = fmaxf(fmaxf(s[4][0],s[4][1]),fmaxf(s[4][2],s[4][3]));
    }
}

// ================= K0b: build Tpack in B-fragment order ======================
// Tpack ushort index: (kb*64 + j)*32 + g*8 + e   where pixel = kb*32 + g*8 + e
__global__ void hm_build_tpack(const int* __restrict__ tm, unsigned short* __restrict__ tp) {
    int bid = blockIdx.x;                 // 64 * 256 blocks
    int j = bid >> 8, chunk = bid & 255;
    int pix = chunk * 256 + threadIdx.x;
    unsigned short v = 0;
    if (j < TNUM) v = (tm[(size_t)j * HW + pix] != 0) ? (unsigned short)0x3F80 : (unsigned short)0;
    size_t idx = ((size_t)(pix >> 5) * 64 + j) * 32 + (size_t)((pix >> 3) & 3) * 8 + (pix & 7);
    tp[idx] = v;
}

// ================= K1: heavy fused MFMA kernel ===============================
__device__ inline void pix_proc(float x, int e, float xfb, float yf,
                                __bf16* P, __bf16* F,
                                float& sp, float& sn,
                                float& xM, float& yM, float& xm, float& ym) {
    float ex = __expf(x);
    float opex = 1.f + ex;
    float om = __builtin_amdgcn_rcpf(opex);   // 1 - p
    float p = 1.f - om;
    float spx = __logf(opex);      // -log(1-p)
    float spmx = spx - x;          // -log(p)
    float pos = (om * om) * (0.25f * spmx);
    float neg = (p * p) * (0.75f * spx);
    sp += p; sn += neg;
    float xf = xfb + (float)e;
    float xmsk = x * xf, ymsk = x * yf;
    xM = fmaxf(xM, xmsk); yM = fmaxf(yM, ymsk);
    bool nz = (x != 0.f);
    xm = fminf(xm, nz ? xmsk : 1e8f);
    ym = fminf(ym, nz ? ymsk : 1e8f);
    P[e] = (__bf16)p;
    F[e] = (__bf16)(pos - neg);
}

// grid: NTIL*PS = 2432 blocks of 256. XCD-swizzled: xcd=id&7, q=id>>3,
// ntile=q%38, psg=q/38 (0..7), ps=xcd+8*psg. All 38 blocks sharing a
// ps-slice of tpack land on one XCD (L2-resident slices).
// Wave w owns pixels [ps*1024 + w*256, +256). A rows = ntile*16..+15.
// Dots are ACCUMULATED via atomicAdd into a tiny [2][608][64] buffer
// (311 KB) after the in-block LDS reduce -- no big dots workspace.
__launch_bounds__(256, 6)
__global__ void hm_heavy(const float* __restrict__ pm, const unsigned short* __restrict__ tp,
                         float* __restrict__ dots, float* __restrict__ stats) {
    int id = blockIdx.x;
    int xcd = id & 7, q = id >> 3;
    int ntile = q % NTIL, psg = q / NTIL;
    int ps = xcd + 8 * psg;               // [0,64)
    int bl = ntile * PS + ps;             // logical block index
    int tid = threadIdx.x, w = tid >> 6, l = tid & 63, g = l >> 4, c = l & 15;
    int n0 = ntile * 16;
    int row = min(n0 + c, NPRED - 1);
    const float* A = pm + (size_t)row * HW;
    const s16x8* tpv = (const s16x8*)tp;
    int pb = ps * 1024 + w * 256;

    f32x4 acc[4][2];
#pragma unroll
    for (int nt = 0; nt < 4; ++nt)
#pragma unroll
        for (int m = 0; m < 2; ++m) acc[nt][m] = (f32x4)0.f;

    float sp = 0.f, sn = 0.f;
    float xM = -INFINITY, yM = -INFINITY, xm = INFINITY, ym = INFINITY;

#pragma unroll 2
    for (int step = 0; step < 8; ++step) {
        int k0 = pb + step * 32;
        int kk = k0 + g * 8;
        float4 aa = *(const float4*)(A + kk);
        float4 ab = *(const float4*)(A + kk + 4);
        float yf = (float)(kk >> 8);
        float xfb = (float)(kk & 255);

        union { __bf16 h[8]; s16x8 v; } P, F;
        float x[8] = {aa.x, aa.y, aa.z, aa.w, ab.x, ab.y, ab.z, ab.w};
#pragma unroll
        for (int e = 0; e < 8; ++e)
            pix_proc(x[e], e, xfb, yf, P.h, F.h, sp, sn, xM, yM, xm, ym);

        int bbase = (k0 >> 5) * 256 + c * 4 + g;
#pragma unroll
        for (int nt = 0; nt < 4; ++nt) {
            s16x8 bf = tpv[bbase + nt * 64];
            acc[nt][0] = __builtin_amdgcn_mfma_f32_16x16x32_bf16(P.v, bf, acc[nt][0], 0, 0, 0);
            acc[nt][1] = __builtin_amdgcn_mfma_f32_16x16x32_bf16(F.v, bf, acc[nt][1], 0, 0, 0);
        }
    }

    // reduce per-row stats over the 4 g-groups (lanes c, c+16, c+32, c+48: same row)
#pragma unroll
    for (int o = 16; o <= 32; o <<= 1) {
        sp += __shfl_xor(sp, o); sn += __shfl_xor(sn, o);
        xM = fmaxf(xM, __shfl_xor(xM, o)); yM = fmaxf(yM, __shfl_xor(yM, o));
        xm = fminf(xm, __shfl_xor(xm, o)); ym = fminf(ym, __shfl_xor(ym, o));
    }

    __shared__ float ldsD[4][16][64];   // 16 KiB, reused across phases
    // ---- phase A: mat=0 (P dots) ----
#pragma unroll
    for (int nt = 0; nt < 4; ++nt)
#pragma unroll
        for (int r = 0; r < 4; ++r)
            ldsD[w][nt * 4 + r][l] = acc[nt][0][r];
    __syncthreads();
    for (int idx = tid; idx < 1024; idx += 256) {
        int rl = (idx >> 6) & 15, col = idx & 63;
        int gg = rl >> 2, rg = rl & 3;
        int nt = col >> 4, cc = col & 15;
        int lane = gg * 16 + cc;
        int off = nt * 4 + rg;
        float s = ldsD[0][off][lane] + ldsD[1][off][lane] + ldsD[2][off][lane] + ldsD[3][off][lane];
        atomicAdd(&dots[(size_t)(n0 + rl) * 64 + col], s);
    }
    __syncthreads();
    // ---- phase B: mat=1 (F dots) ----
#pragma unroll
    for (int nt = 0; nt < 4; ++nt)
#pragma unroll
        for (int r = 0; r < 4; ++r)
            ldsD[w][nt * 4 + r][l] = acc[nt][1][r];
    __syncthreads();
    for (int idx = tid; idx < 1024; idx += 256) {
        int rl = (idx >> 6) & 15, col = idx & 63;
        int gg = rl >> 2, rg = rl & 3;
        int nt = col >> 4, cc = col & 15;
        int lane = gg * 16 + cc;
        int off = nt * 4 + rg;
        float s = ldsD[0][off][lane] + ldsD[1][off][lane] + ldsD[2][off][lane] + ldsD[3][off][lane];
        atomicAdd(&dots[(size_t)NROWP * 64 + (size_t)(n0 + rl) * 64 + col], s);
    }
    __syncthreads();
    // ---- stats phase (alias the same LDS) ----
    float* ldsS = (float*)ldsD;          // [w][row16][6] flat = w*96 + l*6 + s
    if (l < 16) {
        float* so = ldsS + w * 96 + l * 6;
        so[0] = sp; so[1] = sn; so[2] = xM; so[3] = yM; so[4] = xm; so[5] = ym;
    }
    __syncthreads();
    if (tid < 96) {
        int rr = tid / 6, s = tid % 6;
        float a0 = ldsS[0 * 96 + rr * 6 + s], a1 = ldsS[1 * 96 + rr * 6 + s];
        float a2 = ldsS[2 * 96 + rr * 6 + s], a3 = ldsS[3 * 96 + rr * 6 + s];
        float r;
        if (s < 2)      r = a0 + a1 + a2 + a3;
        else if (s < 4) r = fmaxf(fmaxf(a0, a1), fmaxf(a2, a3));
        else            r = fminf(fminf(a0, a1), fminf(a2, a3));
        stats[(size_t)(bl * 16 + rr) * 6 + s] = r;
    }
}

// ================= K2: reduce pred stats over PS slices ======================
__global__ void hm_pred_reduce(const float* __restrict__ stats, float* __restrict__ pstat) {
    int n = blockIdx.x;            // 600
    int l = threadIdx.x;           // 64 (one per ps slice)
    int ntile = n >> 4, r = n & 15;
    const float* sb = stats + ((size_t)((ntile * PS + l) * 16 + r)) * 6;
    float v0 = sb[0], v1 = sb[1], v2 = sb[2], v3 = sb[3], v4 = sb[4], v5 = sb[5];
#pragma unroll
    for (int o = 1; o < 64; o <<= 1) {
        v0 += __shfl_xor(v0, o); v1 += __shfl_xor(v1, o);
        v2 = fmaxf(v2, __shfl_xor(v2, o)); v3 = fmaxf(v3, __shfl_xor(v3, o));
        v4 = fminf(v4, __shfl_xor(v4, o)); v5 = fminf(v5, __shfl_xor(v5, o));
    }
    if (l == 0) {
        float* o = pstat + (size_t)n * 6;
        o[0] = v0; o[1] = v1; o[2] = v2; o[3] = v3; o[4] = v4; o[5] = v5;
    }
}

// ================= helpers ===================================================
__device__ inline float giou2(float ax0, float ay0, float ax1, float ay1,
                              float bx0, float by0, float bx1, float by1) {
    float area1 = (ax1 - ax0) * (ay1 - ay0);
    float area2 = (bx1 - bx0) * (by1 - by0);
    float ltx = fmaxf(ax0, bx0), lty = fmaxf(ay0, by0);
    float rbx = fminf(ax1, bx1), rby = fminf(ay1, by1);
    float iw = fmaxf(rbx - ltx, 0.f), ih = fmaxf(rby - lty, 0.f);
    float inter = iw * ih;
    float uni = area1 + area2 - inter;
    float iou = inter / uni;
    float ex0 = fminf(ax0, bx0), ey0 = fminf(ay0, by0);
    float ex1 = fmaxf(ax1, bx1), ey1 = fmaxf(ay1, by1);
    float ew = fmaxf(ex1 - ex0, 0.f), eh = fmaxf(ey1 - ey0, 0.f);
    float ae = ew * eh;
    return iou - (ae - uni) / ae;
}

__device__ inline float giou_cxcywh(float acx, float acy, float aw, float ah,
                                    float bcx, float bcy, float bw, float bh) {
    return giou2(acx - 0.5f * aw, acy - 0.5f * ah, acx + 0.5f * aw, acy + 0.5f * ah,
                 bcx - 0.5f * bw, bcy - 0.5f * bh, bcx + 0.5f * bw, bcy + 0.5f * bh);
}

// ================= K3: final combine =========================================
__global__ void hm_combine(const float* __restrict__ pred_logits,
                           const float* __restrict__ pred_boxes,
                           const float* __restrict__ tgt_boxes,
                           const int* __restrict__ tgt_ids,
                           const float* __restrict__ dots,
                           const float* __restrict__ pstat,
                           const float* __restrict__ tstat,
                           float* __restrict__ out) {
    int idx = blockIdx.x * blockDim.x + threadIdx.x;
    if (idx >= NPRED * TNUM) return;
    int n = idx / TNUM, j = idx % TNUM;

    float dp = dots[(size_t)n * 64 + j];
    float df = dots[(size_t)NROWP * 64 + (size_t)n * 64 + j];

    // reduce target stats over 8 chunks
    float tcnt = 0.f, txm = INFINITY, tym = INFINITY, txM = -INFINITY, tyM = -INFINITY;
#pragma unroll
    for (int k = 0; k < 8; ++k) {
        const float* tb = tstat + (size_t)(j * 8 + k) * 5;
        tcnt += tb[0];
        txm = fminf(txm, tb[1]); tym = fminf(tym, tb[2]);
        txM = fmaxf(txM, tb[3]); tyM = fmaxf(tyM, tb[4]);
    }

    const float* pp = pstat + (size_t)n * 6;
    float sum_p = pp[0], sum_neg = pp[1];
    float pxM = pp[2], pyM = pp[3], pxm = pp[4], pym = pp[5];

    // L1 bbox cost
    float4 ob = ((const float4*)pred_boxes)[n];
    float4 tb4 = ((const float4*)tgt_boxes)[j];
    float cbbox = fabsf(ob.x - tb4.x) + fabsf(ob.y - tb4.y) + fabsf(ob.z - tb4.z) + fabsf(ob.w - tb4.w);

    // GIoU cost (cxcywh boxes)
    float cgiou = -giou_cxcywh(ob.x, ob.y, ob.z, ob.w, tb4.x, tb4.y, tb4.z, tb4.w);

    // focal classification cost
    int id = tgt_ids[j];
    float lg = pred_logits[(size_t)n * NCLS + id];
    float e = __expf(lg);
    float pr = __fdividef(e, 1.f + e);
    float poscc = 0.25f * (1.f - pr) * (1.f - pr) * (-__logf(pr + 1e-8f));
    float negcc = 0.75f * pr * pr * (-__logf(1.f - pr + 1e-8f));
    float cclass = poscc - negcc;

    // GIoU on mask-derived boxes (faithfully fed through cxcywh conversion)
    float cm2b = -giou_cxcywh(pxm, pym, pxM, pyM, txm, tym, txM, tyM);

    // dice
    float un = sum_p + tcnt;
    float cdice = 1.f - (2.f * dp + 1e-5f) / (un + 1e-5f);

    // mask focal
    float cfocal = (df + sum_neg) * (1.0f / (float)HW);

    out[idx] = cbbox + cclass + cgiou + cm2b + cdice + cfocal;
}

// ================= launcher ==================================================
extern "C" void kernel_launch(void* const* d_in, const int* in_sizes, int n_in,
                              void* d_out, int out_size, void* d_ws, size_t ws_size,
                              hipStream_t stream) {
    const float* pred_logits = (const float*)d_in[0];
    const float* pred_boxes  = (const float*)d_in[1];
    const float* pred_masks  = (const float*)d_in[2];
    const float* tgt_boxes   = (const float*)d_in[3];
    const int*   tgt_ids     = (const int*)d_in[4];
    const int*   tgt_masks   = (const int*)d_in[5];
    float* out = (float*)d_out;

    char* wsb = (char*)d_ws;
    unsigned short* tpack = (unsigned short*)wsb;          // 64*HW*2        = 8,388,608 B
    float* dots  = (float*)(wsb + 8388608);                // 2*608*64*4     =   311,296 B
    float* stats = (float*)(wsb + 8699904);                // 2432*16*6*4    =   933,888 B
    float* pstat = (float*)(wsb + 9633792);                // 600*6*4        =    14,400 B
    float* tstat = (float*)(wsb + 9648192);                // 480*5*4        =     9,600 B
                                                           // total ~9.66 MB

    hipMemsetAsync(dots, 0, 311296, stream);               // zero the atomic accumulators
    hipLaunchKernelGGL(hm_tgt_stats, dim3(TNUM * 8), dim3(256), 0, stream, tgt_masks, tstat);
    hipLaunchKernelGGL(hm_build_tpack, dim3(64 * 256), dim3(256), 0, stream, tgt_masks, tpack);
    hipLaunchKernelGGL(hm_heavy, dim3(NTIL * PS), dim3(256), 0, stream, pred_masks, tpack, dots, stats);
    hipLaunchKernelGGL(hm_pred_reduce, dim3(NPRED), dim3(64), 0, stream, stats, pstat);
    hipLaunchKernelGGL(hm_combine, dim3((NPRED * TNUM + 255) / 256), dim3(256), 0, stream,
                       pred_logits, pred_boxes, tgt_boxes, tgt_ids, dots, pstat, tstat, out);
}

// Round 9
// 96.455 us; speedup vs baseline: 4.0489x; 1.8701x over previous
//
#include <hip/hip_runtime.h>
#include <math.h>

#define HW    65536
#define TNUM  60
#define NPRED 600
#define NCLS  91
#define PS    64      // pixel slices of 1024
#define NTIL  38      // ceil(600/16) M-tiles of 16
#define NROWP 608     // padded rows (38*16)

typedef float f32x4 __attribute__((ext_vector_type(4)));
typedef short s16x8 __attribute__((ext_vector_type(8)));

// ================= K0a: target stats partials (cnt + masks_to_boxes) ==========
__global__ void hm_tgt_stats(const int* __restrict__ tm, float* __restrict__ tstat) {
    int j = blockIdx.x >> 3, chunk = blockIdx.x & 7;
    int tid = threadIdx.x;
    const int* row = tm + (size_t)j * HW + chunk * 8192;
    float cnt = 0.f, xmax = -INFINITY, ymax = -INFINITY, xmin = INFINITY, ymin = INFINITY;
    for (int i = tid; i < 8192; i += 256) {
        int pix = chunk * 8192 + i;
        float t = (float)row[i];
        float xf = (float)(pix & 255), yf = (float)(pix >> 8);
        float xm = t * xf, ym = t * yf;
        cnt += t;
        xmax = fmaxf(xmax, xm); ymax = fmaxf(ymax, ym);
        bool nz = (t != 0.f);
        xmin = fminf(xmin, nz ? xm : 1e8f);
        ymin = fminf(ymin, nz ? ym : 1e8f);
    }
#pragma unroll
    for (int o = 1; o < 64; o <<= 1) {
        cnt += __shfl_xor(cnt, o);
        xmax = fmaxf(xmax, __shfl_xor(xmax, o));
        ymax = fmaxf(ymax, __shfl_xor(ymax, o));
        xmin = fminf(xmin, __shfl_xor(xmin, o));
        ymin = fminf(ymin, __shfl_xor(ymin, o));
    }
    __shared__ float s[5][4];
    int w = tid >> 6;
    if ((tid & 63) == 0) { s[0][w]=cnt; s[1][w]=xmin; s[2][w]=ymin; s[3][w]=xmax; s[4][w]=ymax; }
    __syncthreads();
    if (tid == 0) {
        float* o = tstat + (size_t)(j * 8 + chunk) * 5;
        o[0] = s[0][0]+s[0][1]+s[0][2]+s[0][3];
        o[1] = fminf(fminf(s[1][0],s[1][1]),fminf(s[1][2],s[1][3]));
        o[2] = fminf(fminf(s[2][0],s[2][1]),fminf(s[2][2],s[2][3]));
        o[3] = fmaxf(fmaxf(s[3][0],s[3][1]),fmaxf(s[3][2],s[3][3]));
        o[4] = fmaxf(fmaxf(s[4][0],s[4][1]),fmaxf(s[4][2],s[4][3]));
    }
}

// ================= K0b: build Tpack in B-fragment order ======================
// Tpack ushort index: (kb*64 + j)*32 + g*8 + e   where pixel = kb*32 + g*8 + e
__global__ void hm_build_tpack(const int* __restrict__ tm, unsigned short* __restrict__ tp) {
    int bid = blockIdx.x;                 // 64 * 256 blocks
    int j = bid >> 8, chunk = bid & 255;
    int pix = chunk * 256 + threadIdx.x;
    unsigned short v = 0;
    if (j < TNUM) v = (tm[(size_t)j * HW + pix] != 0) ? (unsigned short)0x3F80 : (unsigned short)0;
    size_t idx = ((size_t)(pix >> 5) * 64 + j) * 32 + (size_t)((pix >> 3) & 3) * 8 + (pix & 7);
    tp[idx] = v;
}

// ================= K1: heavy fused MFMA kernel ===============================
__device__ inline void pix_proc(float x, int e, float xfb, float yf,
                                __bf16* P, __bf16* F,
                                float& sp, float& sn,
                                float& xM, float& yM, float& xm, float& ym) {
    float ex = __expf(x);
    float opex = 1.f + ex;
    float om = __builtin_amdgcn_rcpf(opex);   // 1 - p
    float p = 1.f - om;
    float spx = __logf(opex);      // -log(1-p)
    float spmx = spx - x;          // -log(p)
    float pos = (om * om) * (0.25f * spmx);
    float neg = (p * p) * (0.75f * spx);
    sp += p; sn += neg;
    float xf = xfb + (float)e;
    float xmsk = x * xf, ymsk = x * yf;
    xM = fmaxf(xM, xmsk); yM = fmaxf(yM, ymsk);
    bool nz = (x != 0.f);
    xm = fminf(xm, nz ? xmsk : 1e8f);
    ym = fminf(ym, nz ? ymsk : 1e8f);
    P[e] = (__bf16)p;
    F[e] = (__bf16)(pos - neg);
}

// grid: NTIL*PS = 2432 blocks of 256. XCD-swizzled: xcd=id&7, q=id>>3,
// ntile=q%38, psg=q/38 (0..7), ps=xcd+8*psg. All 38 blocks sharing a
// ps-slice of tpack land on one XCD (L2-resident slices).
// Wave w owns pixels [ps*1024 + w*256, +256). A rows = ntile*16..+15.
// launch_bounds (256,4): VGPR budget 128 -- NO SPILL (R5-R8's WRITE bloat
// was scratch spill from over-tight launch bounds).
__launch_bounds__(256, 4)
__global__ void hm_heavy(const float* __restrict__ pm, const unsigned short* __restrict__ tp,
                         float* __restrict__ dots, float* __restrict__ stats) {
    int id = blockIdx.x;
    int xcd = id & 7, q = id >> 3;
    int ntile = q % NTIL, psg = q / NTIL;
    int ps = xcd + 8 * psg;               // [0,64)
    int bl = ntile * PS + ps;             // logical block index
    int tid = threadIdx.x, w = tid >> 6, l = tid & 63, g = l >> 4, c = l & 15;
    int n0 = ntile * 16;
    int row = min(n0 + c, NPRED - 1);
    const float* A = pm + (size_t)row * HW;
    const s16x8* tpv = (const s16x8*)tp;
    int pb = ps * 1024 + w * 256;

    f32x4 acc[4][2];
#pragma unroll
    for (int nt = 0; nt < 4; ++nt)
#pragma unroll
        for (int m = 0; m < 2; ++m) acc[nt][m] = (f32x4)0.f;

    float sp = 0.f, sn = 0.f;
    float xM = -INFINITY, yM = -INFINITY, xm = INFINITY, ym = INFINITY;

#pragma unroll 2
    for (int step = 0; step < 8; ++step) {
        int k0 = pb + step * 32;
        int kk = k0 + g * 8;
        float4 aa = *(const float4*)(A + kk);
        float4 ab = *(const float4*)(A + kk + 4);
        float yf = (float)(kk >> 8);
        float xfb = (float)(kk & 255);

        union { __bf16 h[8]; s16x8 v; } P, F;
        float x[8] = {aa.x, aa.y, aa.z, aa.w, ab.x, ab.y, ab.z, ab.w};
#pragma unroll
        for (int e = 0; e < 8; ++e)
            pix_proc(x[e], e, xfb, yf, P.h, F.h, sp, sn, xM, yM, xm, ym);

        int bbase = (k0 >> 5) * 256 + c * 4 + g;
#pragma unroll
        for (int nt = 0; nt < 4; ++nt) {
            s16x8 bf = tpv[bbase + nt * 64];
            acc[nt][0] = __builtin_amdgcn_mfma_f32_16x16x32_bf16(P.v, bf, acc[nt][0], 0, 0, 0);
            acc[nt][1] = __builtin_amdgcn_mfma_f32_16x16x32_bf16(F.v, bf, acc[nt][1], 0, 0, 0);
        }
    }

    // reduce per-row stats over the 4 g-groups (lanes c, c+16, c+32, c+48: same row)
#pragma unroll
    for (int o = 16; o <= 32; o <<= 1) {
        sp += __shfl_xor(sp, o); sn += __shfl_xor(sn, o);
        xM = fmaxf(xM, __shfl_xor(xM, o)); yM = fmaxf(yM, __shfl_xor(yM, o));
        xm = fminf(xm, __shfl_xor(xm, o)); ym = fminf(ym, __shfl_xor(ym, o));
    }

    __shared__ float ldsD[4][16][64];   // 16 KiB, reused across phases
    // ---- phase A: mat=0 (P dots) ----
#pragma unroll
    for (int nt = 0; nt < 4; ++nt)
#pragma unroll
        for (int r = 0; r < 4; ++r)
            ldsD[w][nt * 4 + r][l] = acc[nt][0][r];
    __syncthreads();
    for (int idx = tid; idx < 1024; idx += 256) {
        int rl = (idx >> 6) & 15, col = idx & 63;
        int gg = rl >> 2, rg = rl & 3;
        int nt = col >> 4, cc = col & 15;
        int lane = gg * 16 + cc;
        int off = nt * 4 + rg;
        float s = ldsD[0][off][lane] + ldsD[1][off][lane] + ldsD[2][off][lane] + ldsD[3][off][lane];
        atomicAdd(&dots[(size_t)(n0 + rl) * 64 + col], s);
    }
    __syncthreads();
    // ---- phase B: mat=1 (F dots) ----
#pragma unroll
    for (int nt = 0; nt < 4; ++nt)
#pragma unroll
        for (int r = 0; r < 4; ++r)
            ldsD[w][nt * 4 + r][l] = acc[nt][1][r];
    __syncthreads();
    for (int idx = tid; idx < 1024; idx += 256) {
        int rl = (idx >> 6) & 15, col = idx & 63;
        int gg = rl >> 2, rg = rl & 3;
        int nt = col >> 4, cc = col & 15;
        int lane = gg * 16 + cc;
        int off = nt * 4 + rg;
        float s = ldsD[0][off][lane] + ldsD[1][off][lane] + ldsD[2][off][lane] + ldsD[3][off][lane];
        atomicAdd(&dots[(size_t)NROWP * 64 + (size_t)(n0 + rl) * 64 + col], s);
    }
    __syncthreads();
    // ---- stats phase (alias the same LDS) ----
    float* ldsS = (float*)ldsD;          // [w][row16][6] flat = w*96 + l*6 + s
    if (l < 16) {
        float* so = ldsS + w * 96 + l * 6;
        so[0] = sp; so[1] = sn; so[2] = xM; so[3] = yM; so[4] = xm; so[5] = ym;
    }
    __syncthreads();
    if (tid < 96) {
        int rr = tid / 6, s = tid % 6;
        float a0 = ldsS[0 * 96 + rr * 6 + s], a1 = ldsS[1 * 96 + rr * 6 + s];
        float a2 = ldsS[2 * 96 + rr * 6 + s], a3 = ldsS[3 * 96 + rr * 6 + s];
        float r;
        if (s < 2)      r = a0 + a1 + a2 + a3;
        else if (s < 4) r = fmaxf(fmaxf(a0, a1), fmaxf(a2, a3));
        else            r = fminf(fminf(a0, a1), fminf(a2, a3));
        stats[(size_t)(bl * 16 + rr) * 6 + s] = r;
    }
}

// ================= K2: reduce pred stats over PS slices ======================
__global__ void hm_pred_reduce(const float* __restrict__ stats, float* __restrict__ pstat) {
    int n = blockIdx.x;            // 600
    int l = threadIdx.x;           // 64 (one per ps slice)
    int ntile = n >> 4, r = n & 15;
    const float* sb = stats + ((size_t)((ntile * PS + l) * 16 + r)) * 6;
    float v0 = sb[0], v1 = sb[1], v2 = sb[2], v3 = sb[3], v4 = sb[4], v5 = sb[5];
#pragma unroll
    for (int o = 1; o < 64; o <<= 1) {
        v0 += __shfl_xor(v0, o); v1 += __shfl_xor(v1, o);
        v2 = fmaxf(v2, __shfl_xor(v2, o)); v3 = fmaxf(v3, __shfl_xor(v3, o));
        v4 = fminf(v4, __shfl_xor(v4, o)); v5 = fminf(v5, __shfl_xor(v5, o));
    }
    if (l == 0) {
        float* o = pstat + (size_t)n * 6;
        o[0] = v0; o[1] = v1; o[2] = v2; o[3] = v3; o[4] = v4; o[5] = v5;
    }
}

// ================= helpers ===================================================
__device__ inline float giou2(float ax0, float ay0, float ax1, float ay1,
                              float bx0, float by0, float bx1, float by1) {
    float area1 = (ax1 - ax0) * (ay1 - ay0);
    float area2 = (bx1 - bx0) * (by1 - by0);
    float ltx = fmaxf(ax0, bx0), lty = fmaxf(ay0, by0);
    float rbx = fminf(ax1, bx1), rby = fminf(ay1, by1);
    float iw = fmaxf(rbx - ltx, 0.f), ih = fmaxf(rby - lty, 0.f);
    float inter = iw * ih;
    float uni = area1 + area2 - inter;
    float iou = inter / uni;
    float ex0 = fminf(ax0, bx0), ey0 = fminf(ay0, by0);
    float ex1 = fmaxf(ax1, bx1), ey1 = fmaxf(ay1, by1);
    float ew = fmaxf(ex1 - ex0, 0.f), eh = fmaxf(ey1 - ey0, 0.f);
    float ae = ew * eh;
    return iou - (ae - uni) / ae;
}

__device__ inline float giou_cxcywh(float acx, float acy, float aw, float ah,
                                    float bcx, float bcy, float bw, float bh) {
    return giou2(acx - 0.5f * aw, acy - 0.5f * ah, acx + 0.5f * aw, acy + 0.5f * ah,
                 bcx - 0.5f * bw, bcy - 0.5f * bh, bcx + 0.5f * bw, bcy + 0.5f * bh);
}

// ================= K3: final combine =========================================
__global__ void hm_combine(const float* __restrict__ pred_logits,
                           const float* __restrict__ pred_boxes,
                           const float* __restrict__ tgt_boxes,
                           const int* __restrict__ tgt_ids,
                           const float* __restrict__ dots,
                           const float* __restrict__ pstat,
                           const float* __restrict__ tstat,
                           float* __restrict__ out) {
    int idx = blockIdx.x * blockDim.x + threadIdx.x;
    if (idx >= NPRED * TNUM) return;
    int n = idx / TNUM, j = idx % TNUM;

    float dp = dots[(size_t)n * 64 + j];
    float df = dots[(size_t)NROWP * 64 + (size_t)n * 64 + j];

    // reduce target stats over 8 chunks
    float tcnt = 0.f, txm = INFINITY, tym = INFINITY, txM = -INFINITY, tyM = -INFINITY;
#pragma unroll
    for (int k = 0; k < 8; ++k) {
        const float* tb = tstat + (size_t)(j * 8 + k) * 5;
        tcnt += tb[0];
        txm = fminf(txm, tb[1]); tym = fminf(tym, tb[2]);
        txM = fmaxf(txM, tb[3]); tyM = fmaxf(tyM, tb[4]);
    }

    const float* pp = pstat + (size_t)n * 6;
    float sum_p = pp[0], sum_neg = pp[1];
    float pxM = pp[2], pyM = pp[3], pxm = pp[4], pym = pp[5];

    // L1 bbox cost
    float4 ob = ((const float4*)pred_boxes)[n];
    float4 tb4 = ((const float4*)tgt_boxes)[j];
    float cbbox = fabsf(ob.x - tb4.x) + fabsf(ob.y - tb4.y) + fabsf(ob.z - tb4.z) + fabsf(ob.w - tb4.w);

    // GIoU cost (cxcywh boxes)
    float cgiou = -giou_cxcywh(ob.x, ob.y, ob.z, ob.w, tb4.x, tb4.y, tb4.z, tb4.w);

    // focal classification cost
    int id = tgt_ids[j];
    float lg = pred_logits[(size_t)n * NCLS + id];
    float e = __expf(lg);
    float pr = __fdividef(e, 1.f + e);
    float poscc = 0.25f * (1.f - pr) * (1.f - pr) * (-__logf(pr + 1e-8f));
    float negcc = 0.75f * pr * pr * (-__logf(1.f - pr + 1e-8f));
    float cclass = poscc - negcc;

    // GIoU on mask-derived boxes (faithfully fed through cxcywh conversion)
    float cm2b = -giou_cxcywh(pxm, pym, pxM, pyM, txm, tym, txM, tyM);

    // dice
    float un = sum_p + tcnt;
    float cdice = 1.f - (2.f * dp + 1e-5f) / (un + 1e-5f);

    // mask focal
    float cfocal = (df + sum_neg) * (1.0f / (float)HW);

    out[idx] = cbbox + cclass + cgiou + cm2b + cdice + cfocal;
}

// ================= launcher ==================================================
extern "C" void kernel_launch(void* const* d_in, const int* in_sizes, int n_in,
                              void* d_out, int out_size, void* d_ws, size_t ws_size,
                              hipStream_t stream) {
    const float* pred_logits = (const float*)d_in[0];
    const float* pred_boxes  = (const float*)d_in[1];
    const float* pred_masks  = (const float*)d_in[2];
    const float* tgt_boxes   = (const float*)d_in[3];
    const int*   tgt_ids     = (const int*)d_in[4];
    const int*   tgt_masks   = (const int*)d_in[5];
    float* out = (float*)d_out;

    char* wsb = (char*)d_ws;
    unsigned short* tpack = (unsigned short*)wsb;          // 64*HW*2        = 8,388,608 B
    float* dots  = (float*)(wsb + 8388608);                // 2*608*64*4     =   311,296 B
    float* stats = (float*)(wsb + 8699904);                // 2432*16*6*4    =   933,888 B
    float* pstat = (float*)(wsb + 9633792);                // 600*6*4        =    14,400 B
    float* tstat = (float*)(wsb + 9648192);                // 480*5*4        =     9,600 B
                                                           // total ~9.66 MB

    hipMemsetAsync(dots, 0, 311296, stream);               // zero the atomic accumulators
    hipLaunchKernelGGL(hm_tgt_stats, dim3(TNUM * 8), dim3(256), 0, stream, tgt_masks, tstat);
    hipLaunchKernelGGL(hm_build_tpack, dim3(64 * 256), dim3(256), 0, stream, tgt_masks, tpack);
    hipLaunchKernelGGL(hm_heavy, dim3(NTIL * PS), dim3(256), 0, stream, pred_masks, tpack, dots, stats);
    hipLaunchKernelGGL(hm_pred_reduce, dim3(NPRED), dim3(64), 0, stream, stats, pstat);
    hipLaunchKernelGGL(hm_combine, dim3((NPRED * TNUM + 255) / 256), dim3(256), 0, stream,
                       pred_logits, pred_boxes, tgt_boxes, tgt_ids, dots, pstat, tstat, out);
}